// Round 10
// baseline (134.969 us; speedup 1.0000x reference)
//
#include <hip/hip_runtime.h>
#include <hip/hip_bf16.h>
#include <math.h>

#define B_ 512
#define C_ 100000
#define D_ 128
#define CT 128
#define NBLK ((C_ + CT - 1) / CT)   // 782 tiles = grid of main kernel
#define G_ NBLK
#define LOG2E 1.4426950408889634f
#define K2S (6.0f * LOG2E)          // folded: score_log2 = dot * (6*log2e * rsqrt(ss)) - 18*log2e
#define K18S (-18.0f * LOG2E)

typedef __attribute__((ext_vector_type(8))) short short8;  // 8 bf16 (MFMA A/B frag)
typedef __attribute__((ext_vector_type(4))) float f32x4;   // MFMA C/D frag

__device__ __forceinline__ unsigned short f2b(float x) {  // RNE f32->bf16
  union { float f; unsigned int i; } v; v.f = x;
  unsigned int r = v.i + 0x7FFFu + ((v.i >> 16) & 1u);
  return (unsigned short)(r >> 16);
}
__device__ __forceinline__ float b2f(unsigned short u) {
  union { float f; unsigned int i; } v; v.i = ((unsigned int)u) << 16; return v.f;
}

#if defined(__has_builtin)
#if __has_builtin(__builtin_amdgcn_exp2f)
#define EXP2F(x) __builtin_amdgcn_exp2f(x)
#endif
#endif
#ifndef EXP2F
#define EXP2F(x) __expf(0.69314718055994531f * (x))
#endif

// async global -> LDS, 16 B per lane; LDS dest = wave-uniform base, HW adds lane*16
__device__ __forceinline__ void gll16(const void* g, void* l) {
  __builtin_amdgcn_global_load_lds(
      (const __attribute__((address_space(1))) void*)g,
      (__attribute__((address_space(3))) void*)l, 16, 0, 0);
}

// --- kernel A: normalize batch rows to norm 3, store bf16 ---------------------
__global__ __launch_bounds__(256) void batch_norm_kernel(
    const float* __restrict__ batch, unsigned short* __restrict__ xnb)
{
  int lane = threadIdx.x & 63, wv = threadIdx.x >> 6;
  int r = blockIdx.x * 4 + wv;               // grid=128 -> 512 rows
  float2 v = *(const float2*)(batch + (size_t)r * D_ + lane * 2);
  float ss = v.x * v.x + v.y * v.y;
#pragma unroll
  for (int off = 32; off; off >>= 1) ss += __shfl_xor(ss, off);
  float sc = 3.f / fmaxf(sqrtf(ss), 1e-12f);
  ushort2 o; o.x = f2b(v.x * sc); o.y = f2b(v.y * sc);
  *(ushort2*)(xnb + (size_t)r * D_ + lane * 2) = o;
}

// --- main kernel: praw -> LDS (raw f32, gll16) -> in-reg convert -> MFMA+exp --
// grid = NBLK (one 128-col proxy tile per block), 512 threads = 8 waves.
// Wave w computes batch rows [w*64, w*64+64) x all 128 cols of the tile.
// LDS 64KB -> 2 blocks/CU; while one block stages, the other computes.
__global__ __launch_bounds__(512, 4) void pnca_main_kernel(
    const float* __restrict__ praw, const unsigned short* __restrict__ xnb,
    float* __restrict__ pt)
{
  __shared__ __align__(16) float fbuf[CT * D_];   // 64 KB raw f32, swizzled 16B units

  const int tid  = threadIdx.x;
  const int lane = tid & 63;
  const int w    = tid >> 6;
  const int ll   = lane & 15;
  const int lq   = lane >> 4;
  const int t    = blockIdx.x;

  // ---- stage: 8 gll16 rounds; LDS linear, global source inverse-swizzled.
  // slot s = k*512 + tid ; c = s>>5 (tile col), up = s&31 (physical 16B unit),
  // logical unit u = up ^ (c&7); global 16B unit = row(c)*32 + u.
  {
    const unsigned char* gb = (const unsigned char*)praw;
    unsigned char* lb = (unsigned char*)fbuf;
#pragma unroll
    for (int k = 0; k < 8; ++k) {
      int s  = k * 512 + tid;
      int c  = s >> 5;
      int u  = (s & 31) ^ (c & 7);
      int row = t * CT + c; if (row >= C_) row = C_ - 1;
      gll16(gb + ((size_t)row * 32 + u) * 16, lb + (size_t)(k * 512 + w * 64) * 16);
    }
  }

  // A fragments: this wave's 64 rows of xnb (L2-hot), while staging is in flight
  short8 a[4][4];
#pragma unroll
  for (int m = 0; m < 4; ++m)
#pragma unroll
    for (int ks = 0; ks < 4; ++ks)
      a[m][ks] = *(const short8*)(xnb + (size_t)(w * 64 + m * 16 + ll) * D_ + ks * 32 + lq * 8);

  __syncthreads();   // drains vmcnt(0): staged tile complete

  float part[4][4];
#pragma unroll
  for (int m = 0; m < 4; ++m)
#pragma unroll
    for (int r = 0; r < 4; ++r) part[m][r] = 0.f;

#pragma unroll
  for (int g = 0; g < 8; ++g) {
    const int c = g * 16 + ll;            // tile-local col this lane owns
    // this lane's 32 dims of col c: units u = ks*8 + lq*2 + h, swizzled
    float4 vv[8];
#pragma unroll
    for (int j = 0; j < 8; ++j) {
      int u  = (j >> 1) * 8 + lq * 2 + (j & 1);
      int pu = u ^ (c & 7);
      vv[j] = *(const float4*)((const unsigned char*)fbuf + ((size_t)c * 32 + pu) * 16);
    }
    // exact f32 column norm: 32 dims here, + cross-lq shuffles for the rest
    float ss = 0.f;
#pragma unroll
    for (int j = 0; j < 8; ++j)
      ss += vv[j].x * vv[j].x + vv[j].y * vv[j].y + vv[j].z * vv[j].z + vv[j].w * vv[j].w;
    ss += __shfl_xor(ss, 16);
    ss += __shfl_xor(ss, 32);
    float s2 = K2S * __frsqrt_rn(fmaxf(ss, 1e-24f));
    float qn = (t * CT + c < C_) ? K18S : -1e30f;
    // convert to bf16 B-frags (packed pairs -> cvt_pk)
    short8 bfr[4];
#pragma unroll
    for (int ks = 0; ks < 4; ++ks) {
      union { short8 s8; __hip_bfloat162 h[4]; } uc;
      float4 x0 = vv[ks * 2], x1 = vv[ks * 2 + 1];
      uc.h[0] = __float22bfloat162_rn(make_float2(x0.x, x0.y));
      uc.h[1] = __float22bfloat162_rn(make_float2(x0.z, x0.w));
      uc.h[2] = __float22bfloat162_rn(make_float2(x1.x, x1.y));
      uc.h[3] = __float22bfloat162_rn(make_float2(x1.z, x1.w));
      bfr[ks] = uc.s8;
    }
    f32x4 acc[4];
#pragma unroll
    for (int m = 0; m < 4; ++m) acc[m] = (f32x4){0.f, 0.f, 0.f, 0.f};
#pragma unroll
    for (int ks = 0; ks < 4; ++ks)
#pragma unroll
      for (int m = 0; m < 4; ++m)
        acc[m] = __builtin_amdgcn_mfma_f32_16x16x32_bf16(a[m][ks], bfr[ks], acc[m], 0, 0, 0);
#pragma unroll
    for (int m = 0; m < 4; ++m)
#pragma unroll
      for (int r = 0; r < 4; ++r)
        part[m][r] += EXP2F(fmaf(acc[m][r], s2, qn));
  }

  // 16-lane reduce, write per-tile partials; C/D layout: col=ll, row=lq*4+r
#pragma unroll
  for (int m = 0; m < 4; ++m)
#pragma unroll
    for (int r = 0; r < 4; ++r) {
      float v = part[m][r];
      v += __shfl_xor(v, 1);
      v += __shfl_xor(v, 2);
      v += __shfl_xor(v, 4);
      v += __shfl_xor(v, 8);
      if (ll == 0)
        pt[(size_t)t * B_ + w * 64 + m * 16 + lq * 4 + r] = v;
    }
}

// --- kernel 3: per-row combine + positive distance + loss ---------------------
__global__ __launch_bounds__(256) void finalize_rows_kernel(
    const float* __restrict__ praw, const unsigned short* __restrict__ xnb,
    const int* __restrict__ labels, const float* __restrict__ pt,
    float* __restrict__ lossb)
{
  int lane = threadIdx.x & 63, wv = threadIdx.x >> 6;
  int row = blockIdx.x * 4 + wv;             // grid=128 -> 512 rows
  int lab = labels[row];
  float2 pv = *(const float2*)(praw + (size_t)lab * D_ + lane * 2);
  ushort2 xv = *(const ushort2*)(xnb + (size_t)row * D_ + lane * 2);
  float xa = b2f(xv.x), xb = b2f(xv.y);
  float ssp = pv.x * pv.x + pv.y * pv.y;
  float dp  = xa * pv.x + xb * pv.y;
#pragma unroll
  for (int off = 32; off; off >>= 1) {
    ssp += __shfl_xor(ssp, off);
    dp  += __shfl_xor(dp, off);
  }
  float pd = 18.f - 2.f * dp * (3.f / fmaxf(sqrtf(ssp), 1e-12f));  // positive dist
  float s = 0.f;
  for (int gg = lane; gg < G_; gg += 64) s += pt[(size_t)gg * B_ + row];
#pragma unroll
  for (int off = 32; off; off >>= 1) s += __shfl_xor(s, off);
  if (lane == 0) lossb[row] = pd + logf(s - __expf(-pd));
}

// --- kernel 4: mean over 512 rows ---------------------------------------------
__global__ __launch_bounds__(512) void reduce_mean_kernel(
    const float* __restrict__ lossb, float* __restrict__ out)
{
  int t = threadIdx.x;
  float v = lossb[t];
#pragma unroll
  for (int off = 1; off < 64; off <<= 1) v += __shfl_xor(v, off);
  __shared__ float red[8];
  if ((t & 63) == 0) red[t >> 6] = v;
  __syncthreads();
  if (t == 0) {
    float tot = 0.f;
    for (int i = 0; i < 8; ++i) tot += red[i];
    out[0] = tot / (float)B_;
  }
}

extern "C" void kernel_launch(void* const* d_in, const int* in_sizes, int n_in,
                              void* d_out, int out_size, void* d_ws, size_t ws_size,
                              hipStream_t stream)
{
  const float* batch   = (const float*)d_in[0];
  const int*   labels  = (const int*)d_in[1];
  const float* proxies = (const float*)d_in[2];
  float* out = (float*)d_out;

  unsigned char* ws = (unsigned char*)d_ws;
  unsigned short* xnb = (unsigned short*)ws;                   // 128 KB
  float* pt    = (float*)(ws + 131072);                        // 782*512*4 ~= 1.6 MB
  float* lossb = (float*)(ws + 131072 + (size_t)G_ * B_ * 4);  // 2 KB

  batch_norm_kernel<<<B_ / 4, 256, 0, stream>>>(batch, xnb);
  pnca_main_kernel<<<NBLK, 512, 0, stream>>>(proxies, xnb, pt);
  finalize_rows_kernel<<<B_ / 4, 256, 0, stream>>>(proxies, xnb, labels, pt, lossb);
  reduce_mean_kernel<<<1, 512, 0, stream>>>(lossb, out);
}

// Round 11
// 72.938 us; speedup vs baseline: 1.8505x; 1.8505x over previous
//
#include <hip/hip_runtime.h>
#include <hip/hip_bf16.h>
#include <math.h>

#define B_ 512
#define C_ 100000
#define D_ 128
#define CT 128
#define NBLK ((C_ + CT - 1) / CT)   // 782 tiles = grid of main kernel
#define G_ NBLK
#define LOG2E 1.4426950408889634f
#define K2S (6.0f * LOG2E)          // score_log2 = dot * (6*log2e*rsqrt(ss)) - 18*log2e
#define K18S (-18.0f * LOG2E)

typedef __attribute__((ext_vector_type(8))) short short8;  // 8 bf16 (MFMA A/B frag)
typedef __attribute__((ext_vector_type(4))) float f32x4;   // MFMA C/D frag

__device__ __forceinline__ unsigned short f2b(float x) {  // RNE f32->bf16
  union { float f; unsigned int i; } v; v.f = x;
  unsigned int r = v.i + 0x7FFFu + ((v.i >> 16) & 1u);
  return (unsigned short)(r >> 16);
}
__device__ __forceinline__ float b2f(unsigned short u) {
  union { float f; unsigned int i; } v; v.i = ((unsigned int)u) << 16; return v.f;
}

#if defined(__has_builtin)
#if __has_builtin(__builtin_amdgcn_exp2f)
#define EXP2F(x) __builtin_amdgcn_exp2f(x)
#endif
#endif
#ifndef EXP2F
#define EXP2F(x) __expf(0.69314718055994531f * (x))
#endif

// async global -> LDS, 16 B per lane; LDS dest = wave-uniform base, HW adds lane*16
__device__ __forceinline__ void gll16(const void* g, void* l) {
  __builtin_amdgcn_global_load_lds(
      (const __attribute__((address_space(1))) void*)g,
      (__attribute__((address_space(3))) void*)l, 16, 0, 0);
}

// --- kernel A: normalize batch rows to norm 3, store bf16 ---------------------
__global__ __launch_bounds__(256) void batch_norm_kernel(
    const float* __restrict__ batch, unsigned short* __restrict__ xnb)
{
  int lane = threadIdx.x & 63, wv = threadIdx.x >> 6;
  int r = blockIdx.x * 4 + wv;               // grid=128 -> 512 rows
  float2 v = *(const float2*)(batch + (size_t)r * D_ + lane * 2);
  float ss = v.x * v.x + v.y * v.y;
#pragma unroll
  for (int off = 32; off; off >>= 1) ss += __shfl_xor(ss, off);
  float sc = 3.f / fmaxf(sqrtf(ss), 1e-12f);
  ushort2 o; o.x = f2b(v.x * sc); o.y = f2b(v.y * sc);
  *(ushort2*)(xnb + (size_t)r * D_ + lane * 2) = o;
}

// --- main kernel: praw -> LDS (raw f32, gll16) -> in-reg convert -> MFMA+exp --
// grid = NBLK (one 128-col proxy tile per block), 512 threads = 8 waves.
// Two sequential row-halves per tile: wave w does rows h*256 + w*32 .. +32.
// Keeps live VGPRs ~90 (R10 spilled: 150 demand under a 64-reg cap).
__global__ __launch_bounds__(512, 2) void pnca_main_kernel(
    const float* __restrict__ praw, const unsigned short* __restrict__ xnb,
    float* __restrict__ pt)
{
  __shared__ __align__(16) float fbuf[CT * D_];   // 64 KB raw f32, swizzled 16B units

  const int tid  = threadIdx.x;
  const int lane = tid & 63;
  const int w    = tid >> 6;
  const int ll   = lane & 15;
  const int lq   = lane >> 4;
  const int t    = blockIdx.x;

  // ---- stage: 8 gll16 rounds; LDS linear, global source inverse-swizzled.
  // slot s = k*512 + tid ; c = s>>5 (tile col), up = s&31 (physical 16B unit),
  // logical unit u = up ^ (c&7); global 16B unit = row(c)*32 + u.
  {
    const unsigned char* gb = (const unsigned char*)praw;
    unsigned char* lb = (unsigned char*)fbuf;
#pragma unroll
    for (int k = 0; k < 8; ++k) {
      int s  = k * 512 + tid;
      int c  = s >> 5;
      int u  = (s & 31) ^ (c & 7);
      int row = t * CT + c; if (row >= C_) row = C_ - 1;
      gll16(gb + ((size_t)row * 32 + u) * 16, lb + (size_t)(k * 512 + w * 64) * 16);
    }
  }
  __syncthreads();   // drains vmcnt(0): staged tile complete

#pragma unroll
  for (int h = 0; h < 2; ++h) {
    const int rbase = h * 256 + w * 32;

    // A fragments: this wave's 32 rows of xnb (L2-hot)
    short8 a[2][4];
#pragma unroll
    for (int m = 0; m < 2; ++m)
#pragma unroll
      for (int ks = 0; ks < 4; ++ks)
        a[m][ks] = *(const short8*)(xnb + (size_t)(rbase + m * 16 + ll) * D_ + ks * 32 + lq * 8);

    float part[2][4];
#pragma unroll
    for (int m = 0; m < 2; ++m)
#pragma unroll
      for (int r = 0; r < 4; ++r) part[m][r] = 0.f;

#pragma unroll
    for (int g = 0; g < 8; ++g) {
      const int c = g * 16 + ll;          // tile-local col this lane owns
      // read this lane's 32 dims of col c one float4 at a time: norm + cvt
      float ss = 0.f;
      short8 bfr[4];
#pragma unroll
      for (int ks = 0; ks < 4; ++ks) {
        union { short8 s8; __hip_bfloat162 hh[4]; } uc;
#pragma unroll
        for (int half16 = 0; half16 < 2; ++half16) {
          int u  = ks * 8 + lq * 2 + half16;
          int pu = u ^ (c & 7);
          float4 v = *(const float4*)((const unsigned char*)fbuf + ((size_t)c * 32 + pu) * 16);
          ss += v.x * v.x + v.y * v.y + v.z * v.z + v.w * v.w;
          uc.hh[half16 * 2]     = __float22bfloat162_rn(make_float2(v.x, v.y));
          uc.hh[half16 * 2 + 1] = __float22bfloat162_rn(make_float2(v.z, v.w));
        }
        bfr[ks] = uc.s8;
      }
      ss += __shfl_xor(ss, 16);
      ss += __shfl_xor(ss, 32);
      float s2 = K2S * __frsqrt_rn(fmaxf(ss, 1e-24f));
      float qn = (t * CT + c < C_) ? K18S : -1e30f;

      f32x4 acc0 = (f32x4){0.f, 0.f, 0.f, 0.f};
      f32x4 acc1 = (f32x4){0.f, 0.f, 0.f, 0.f};
#pragma unroll
      for (int ks = 0; ks < 4; ++ks) {
        acc0 = __builtin_amdgcn_mfma_f32_16x16x32_bf16(a[0][ks], bfr[ks], acc0, 0, 0, 0);
        acc1 = __builtin_amdgcn_mfma_f32_16x16x32_bf16(a[1][ks], bfr[ks], acc1, 0, 0, 0);
      }
#pragma unroll
      for (int r = 0; r < 4; ++r) {
        part[0][r] += EXP2F(fmaf(acc0[r], s2, qn));
        part[1][r] += EXP2F(fmaf(acc1[r], s2, qn));
      }
    }

    // 16-lane reduce, write per-tile partials; C/D layout: col=ll, row=lq*4+r
#pragma unroll
    for (int m = 0; m < 2; ++m)
#pragma unroll
      for (int r = 0; r < 4; ++r) {
        float v = part[m][r];
        v += __shfl_xor(v, 1);
        v += __shfl_xor(v, 2);
        v += __shfl_xor(v, 4);
        v += __shfl_xor(v, 8);
        if (ll == 0)
          pt[(size_t)t * B_ + rbase + m * 16 + lq * 4 + r] = v;
      }
  }
}

// --- kernel 3: per-row combine + positive distance + loss ---------------------
__global__ __launch_bounds__(256) void finalize_rows_kernel(
    const float* __restrict__ praw, const unsigned short* __restrict__ xnb,
    const int* __restrict__ labels, const float* __restrict__ pt,
    float* __restrict__ lossb)
{
  int lane = threadIdx.x & 63, wv = threadIdx.x >> 6;
  int row = blockIdx.x * 4 + wv;             // grid=128 -> 512 rows
  int lab = labels[row];
  float2 pv = *(const float2*)(praw + (size_t)lab * D_ + lane * 2);
  ushort2 xv = *(const ushort2*)(xnb + (size_t)row * D_ + lane * 2);
  float xa = b2f(xv.x), xb = b2f(xv.y);
  float ssp = pv.x * pv.x + pv.y * pv.y;
  float dp  = xa * pv.x + xb * pv.y;
#pragma unroll
  for (int off = 32; off; off >>= 1) {
    ssp += __shfl_xor(ssp, off);
    dp  += __shfl_xor(dp, off);
  }
  float pd = 18.f - 2.f * dp * (3.f / fmaxf(sqrtf(ssp), 1e-12f));  // positive dist
  float s = 0.f;
  for (int gg = lane; gg < G_; gg += 64) s += pt[(size_t)gg * B_ + row];
#pragma unroll
  for (int off = 32; off; off >>= 1) s += __shfl_xor(s, off);
  if (lane == 0) lossb[row] = pd + logf(s - __expf(-pd));
}

// --- kernel 4: mean over 512 rows ---------------------------------------------
__global__ __launch_bounds__(512) void reduce_mean_kernel(
    const float* __restrict__ lossb, float* __restrict__ out)
{
  int t = threadIdx.x;
  float v = lossb[t];
#pragma unroll
  for (int off = 1; off < 64; off <<= 1) v += __shfl_xor(v, off);
  __shared__ float red[8];
  if ((t & 63) == 0) red[t >> 6] = v;
  __syncthreads();
  if (t == 0) {
    float tot = 0.f;
    for (int i = 0; i < 8; ++i) tot += red[i];
    out[0] = tot / (float)B_;
  }
}

extern "C" void kernel_launch(void* const* d_in, const int* in_sizes, int n_in,
                              void* d_out, int out_size, void* d_ws, size_t ws_size,
                              hipStream_t stream)
{
  const float* batch   = (const float*)d_in[0];
  const int*   labels  = (const int*)d_in[1];
  const float* proxies = (const float*)d_in[2];
  float* out = (float*)d_out;

  unsigned char* ws = (unsigned char*)d_ws;
  unsigned short* xnb = (unsigned short*)ws;                   // 128 KB
  float* pt    = (float*)(ws + 131072);                        // 782*512*4 ~= 1.6 MB
  float* lossb = (float*)(ws + 131072 + (size_t)G_ * B_ * 4);  // 2 KB

  batch_norm_kernel<<<B_ / 4, 256, 0, stream>>>(batch, xnb);
  pnca_main_kernel<<<NBLK, 512, 0, stream>>>(proxies, xnb, pt);
  finalize_rows_kernel<<<B_ / 4, 256, 0, stream>>>(proxies, xnb, labels, pt, lossb);
  reduce_mean_kernel<<<1, 512, 0, stream>>>(lossb, out);
}